// Round 12
// baseline (183.432 us; speedup 1.0000x reference)
//
#include <hip/hip_runtime.h>
#include <hip/hip_bf16.h>

// MultiHeadAttention: B=4, T=2048, DIM=64, H=12. fp32 I/O.
// Flat-reshape semantics: QKV are (8192,768) row-major; attention slices are
// contiguous 131072-elem chunks. Roles: queries = K rows (i), keys = Q rows
// (j), values = V rows, softmax over j.
// Round 20: r19's per-block vtrans fusion was WRONG (flat reshape: qkv tile
// (rt,h) -> stride-12 scattered t_global = grow*12+h, not a contiguous slice
// chunk). Correct fusion: attn reads V slices DIRECTLY ([2048][64] row-major,
// same addressing as Q) and transposes [t][d]->[d][t] during LDS staging
// with vtrans's verified XOR-swizzle pair: write value(t,d) at
// V[d*LDQ + ((t>>3)^(d>>3))*8 + (t&7)]; PV group-m read at
// d*LDQ + ((js*4+m)^(d>>3))*8 + 4hi  (slot algebra: t = js*32+8m+4hi+e).
// vtrans kernel + Vt buffer deleted; Z gets its own buffer (attn reads V).
// qkv = round-0 verbatim (y=2, best measured). out/prep = round-6 verbatim.

#define DIM 64
#define NH 12
#define HD 768
#define BT 8192
#define TSEQ 2048
#define NSLICE 48
#define SLICE (TSEQ*DIM)

#define LDQ 72   // LDS row stride (ushorts)

typedef unsigned short ushort;
typedef __attribute__((ext_vector_type(8))) short bf16x8;
typedef __attribute__((ext_vector_type(4))) short bf16x4;
typedef __attribute__((ext_vector_type(4))) float f32x4;
typedef __attribute__((ext_vector_type(16))) float f32x16;
typedef __attribute__((ext_vector_type(4))) unsigned int uint32x4;

#define SCALE2 0.18033688011112042f   // 0.125 * log2(e)

__device__ __forceinline__ ushort f2b(float f) {
    union { float f; unsigned int i; } v; v.f = f;
    unsigned int x = v.i;
    return (ushort)((x + 0x7fffu + ((x >> 16) & 1u)) >> 16);  // RNE
}

// ---------------- prep: transpose + convert weights ------------------------
// 48 blocks: z = bx/12 (Wq,Wk,Wv,Wo), tile = bx%12.
__global__ __launch_bounds__(256) void prep_w(
    const float* __restrict__ Wq, const float* __restrict__ Wk,
    const float* __restrict__ Wv, const float* __restrict__ Wo,
    ushort* __restrict__ Wt, ushort* __restrict__ Wot)
{
    __shared__ float tile[64][65];
    int bx = blockIdx.x;
    int z = bx / 12, bt = bx % 12;
    const float* __restrict__ IN = (z == 0) ? Wq : (z == 1) ? Wk : (z == 2) ? Wv : Wo;
    int inStride  = (z < 3) ? HD : DIM;
    int outStride = (z < 3) ? DIM : HD;
    int rbase = (z < 3) ? 0 : bt * 64;
    int cbase = (z < 3) ? bt * 64 : 0;
    ushort* __restrict__ OUT = (z < 3) ? (Wt + (size_t)z * HD * DIM) : Wot;
    int t = threadIdx.x;
    int r = t >> 2, c0 = (t & 3) * 16;
    #pragma unroll
    for (int cc = 0; cc < 16; cc += 4) {
        float4 a = *(const float4*)&IN[(size_t)(rbase + r) * inStride + cbase + c0 + cc];
        tile[r][c0 + cc] = a.x; tile[r][c0 + cc + 1] = a.y;
        tile[r][c0 + cc + 2] = a.z; tile[r][c0 + cc + 3] = a.w;
    }
    __syncthreads();
    int cl = t >> 2, r0 = (t & 3) * 16;
    ushort tmp[16] __attribute__((aligned(16)));
    #pragma unroll
    for (int rr = 0; rr < 16; ++rr) tmp[rr] = f2b(tile[r0 + rr][cl]);
    *(float4*)&OUT[(size_t)(cbase + cl) * outStride + rbase + r0] = *(const float4*)tmp;
    *(float4*)&OUT[(size_t)(cbase + cl) * outStride + rbase + r0 + 8] = *(const float4*)&tmp[8];
}

// ---------------- Kernel 1: Q/K/V = x @ W (MFMA; x read as fp32) -----------
// Round-0 verbatim: grid (128 row-tiles, 2 halves), 256 thr = 4 waves; wave
// owns 16 rows and loops 18 col-tiles. Q written pre-scaled by SCALE2.
__global__ __launch_bounds__(256) void qkv_kernel(
    const float* __restrict__ x, const ushort* __restrict__ Wt,
    ushort* __restrict__ Q, ushort* __restrict__ K, ushort* __restrict__ V)
{
    int rt = blockIdx.x, half = blockIdx.y;
    int t = threadIdx.x, w = t >> 6, lane = t & 63;
    int ln = lane & 15, q = lane >> 4;
    int m0 = rt * 64 + w * 16;

    // A-frags from fp32 x, converted in-reg (once per wave)
    float4 xa = *(const float4*)&x[(size_t)(m0 + ln) * DIM + q * 8];
    float4 xb_ = *(const float4*)&x[(size_t)(m0 + ln) * DIM + q * 8 + 4];
    float4 xc = *(const float4*)&x[(size_t)(m0 + ln) * DIM + 32 + q * 8];
    float4 xd = *(const float4*)&x[(size_t)(m0 + ln) * DIM + 32 + q * 8 + 4];
    ushort ta[8] __attribute__((aligned(16)));
    ushort tb[8] __attribute__((aligned(16)));
    ta[0]=f2b(xa.x); ta[1]=f2b(xa.y); ta[2]=f2b(xa.z); ta[3]=f2b(xa.w);
    ta[4]=f2b(xb_.x); ta[5]=f2b(xb_.y); ta[6]=f2b(xb_.z); ta[7]=f2b(xb_.w);
    tb[0]=f2b(xc.x); tb[1]=f2b(xc.y); tb[2]=f2b(xc.z); tb[3]=f2b(xc.w);
    tb[4]=f2b(xd.x); tb[5]=f2b(xd.y); tb[6]=f2b(xd.z); tb[7]=f2b(xd.w);
    bf16x8 af0 = *(const bf16x8*)ta;
    bf16x8 af1 = *(const bf16x8*)tb;

    for (int cc = 0; cc < 18; ++cc) {
        int ct = half * 18 + cc;
        int which = ct / 12;
        int col0 = (ct % 12) * 64;
        const ushort* __restrict__ Wz = Wt + (size_t)which * HD * DIM;  // (768x64)
        ushort* __restrict__ Y = (which == 0) ? Q : (which == 1) ? K : V;
        float sc = (which == 0) ? SCALE2 : 1.f;
        #pragma unroll
        for (int nt = 0; nt < 4; ++nt) {
            int n = col0 + nt * 16 + ln;
            bf16x8 bf0 = *(const bf16x8*)&Wz[(size_t)n * DIM + q * 8];
            bf16x8 bf1 = *(const bf16x8*)&Wz[(size_t)n * DIM + 32 + q * 8];
            f32x4 acc = (f32x4){0.f, 0.f, 0.f, 0.f};
            acc = __builtin_amdgcn_mfma_f32_16x16x32_bf16(af0, bf0, acc, 0, 0, 0);
            acc = __builtin_amdgcn_mfma_f32_16x16x32_bf16(af1, bf1, acc, 0, 0, 0);
            #pragma unroll
            for (int r = 0; r < 4; ++r)
                Y[(size_t)(m0 + q * 4 + r) * HD + col0 + nt * 16 + ln] = f2b(acc[r] * sc);
        }
    }
}

// ---------------- Kernel 2: MFMA flash attention (32x32, fused V-trans) ----
// r13 core with V read DIRECTLY from the flat V slices ([2048][64], same
// addressing as Q) and transposed during LDS staging via the verified
// vtrans XOR-swizzle: value(t,d) -> Vtile[d*LDQ + ((t>>3)^(d>>3))*8 + (t&7)].
// PV reads un-swizzle per 8-group: group m of js at
// d*LDQ + ((js*4+m)^(d>>3))*8 + 4hi  (=> t = js*32+8m+4hi+e, the exact
// groups the verified core consumed). Everything else r13 verbatim.
__global__ __launch_bounds__(256, 3) void attn_kernel(
    const ushort* __restrict__ Qs, const ushort* __restrict__ Ks,
    const ushort* __restrict__ Vs, ushort* __restrict__ Zs)
{
    __shared__ ushort sh[4 * 64 * LDQ];   // [Qt0][Qt1][Vt0][Vt1]; epilogue reuses
    int itile = blockIdx.x, s = blockIdx.y;
    const ushort* __restrict__ Qp = Qs + (size_t)s * SLICE;
    const ushort* __restrict__ Kp = Ks + (size_t)s * SLICE;
    const ushort* __restrict__ Vp = Vs + (size_t)s * SLICE;    // [2048][64] flat
    ushort* __restrict__ Zp = Zs + (size_t)s * SLICE;
    int t = threadIdx.x, w = t >> 6, lane = t & 63;
    int i5 = lane & 31, hi = lane >> 5;

    // K fragments (B-operand): lane holds K[i0+i5][c*16 + hi*8 + e]
    bf16x8 kf[4];
    {
        size_t krow = (size_t)(itile * 128 + w * 32 + i5) * DIM;
        #pragma unroll
        for (int c = 0; c < 4; ++c)
            kf[c] = *(const bf16x8*)&Kp[krow + c * 16 + hi * 8];
    }

    f32x16 Of0, Of1;
    #pragma unroll
    for (int r = 0; r < 16; ++r) { Of0[r] = 0.f; Of1[r] = 0.f; }
    float lsum = 0.f;

    int sr = t >> 3, sc = (t & 7) * 8;
    const ushort* qsrc0 = &Qp[(size_t)sr * DIM + sc];
    const ushort* qsrc1 = &Qp[(size_t)(sr + 32) * DIM + sc];
    const ushort* vsrc0 = &Vp[(size_t)sr * DIM + sc];
    const ushort* vsrc1 = &Vp[(size_t)(sr + 32) * DIM + sc];
    // vtrans writer swizzle bases: rows sr and sr+32 ((sr+32)>>3 = (sr>>3)+4)
    int b0 = (((sr >> 3) ^ (sc >> 3)) << 3) + (sr & 7);
    int b1 = ((((sr >> 3) + 4) ^ (sc >> 3)) << 3) + (sr & 7);

    // prologue: tile 0 -> buf 0, prefetch tile 1 into regs
    float4 qa0 = *(const float4*)qsrc0;
    float4 qa1 = *(const float4*)qsrc1;
    float4 va0 = *(const float4*)vsrc0;
    float4 va1 = *(const float4*)vsrc1;
    {
        ushort* V0 = sh + 2 * 64 * LDQ;
        *(float4*)&sh[sr * LDQ + sc] = qa0;
        *(float4*)&sh[(sr + 32) * LDQ + sc] = qa1;
        ushort u0[8] __attribute__((aligned(16)));
        ushort u1[8] __attribute__((aligned(16)));
        *(float4*)u0 = va0; *(float4*)u1 = va1;
        #pragma unroll
        for (int k = 0; k < 8; ++k) {
            V0[(sc + k) * LDQ + b0] = u0[k];
            V0[(sc + k) * LDQ + b1] = u1[k];
        }
    }
    qa0 = *(const float4*)(qsrc0 + 64 * DIM);
    qa1 = *(const float4*)(qsrc1 + 64 * DIM);
    va0 = *(const float4*)(vsrc0 + 64 * DIM);
    va1 = *(const float4*)(vsrc1 + 64 * DIM);
    __syncthreads();

    for (int tt = 0; tt < 32; ++tt) {
        int ib = tt & 1;
        const ushort* Qc = sh + ib * (64 * LDQ);
        const ushort* Vc = sh + (2 + ib) * (64 * LDQ);
        // stage next tile into the other buffer; issue loads for tile tt+2
        if (tt < 31) {
            ushort* Qn = sh + (ib ^ 1) * (64 * LDQ);
            ushort* Vn = sh + (2 + (ib ^ 1)) * (64 * LDQ);
            *(float4*)&Qn[sr * LDQ + sc] = qa0;
            *(float4*)&Qn[(sr + 32) * LDQ + sc] = qa1;
            ushort u0[8] __attribute__((aligned(16)));
            ushort u1[8] __attribute__((aligned(16)));
            *(float4*)u0 = va0; *(float4*)u1 = va1;
            #pragma unroll
            for (int k = 0; k < 8; ++k) {
                Vn[(sc + k) * LDQ + b0] = u0[k];
                Vn[(sc + k) * LDQ + b1] = u1[k];
            }
            if (tt < 30) {
                size_t qo = (size_t)(tt + 2) * 64 * DIM;
                qa0 = *(const float4*)(qsrc0 + qo);
                qa1 = *(const float4*)(qsrc1 + qo);
                va0 = *(const float4*)(vsrc0 + qo);
                va1 = *(const float4*)(vsrc1 + qo);
            }
        }
        #pragma unroll
        for (int js = 0; js < 2; ++js) {
            // S^T (32j x 32i), Q pre-scaled: S already in log2-units
            f32x16 acc;
            #pragma unroll
            for (int r = 0; r < 16; ++r) acc[r] = 0.f;
            #pragma unroll
            for (int c = 0; c < 4; ++c) {
                bf16x8 aQ = *(const bf16x8*)&Qc[(js * 32 + i5) * LDQ + c * 16 + hi * 8];
                acc = __builtin_amdgcn_mfma_f32_32x32x16_bf16(aQ, kf[c], acc, 0, 0, 0);
            }
            // p = exp2(S); truncation-pack pairs (low short = even reg);
            // l summed from the truncated values (matches P exactly)
            unsigned wv[8];
            float ls = 0.f;
            #pragma unroll
            for (int k = 0; k < 8; ++k) {
                float p0 = __builtin_amdgcn_exp2f(acc[2 * k]);
                float p1 = __builtin_amdgcn_exp2f(acc[2 * k + 1]);
                unsigned int bb0 = __float_as_uint(p0), bb1 = __float_as_uint(p1);
                unsigned int t1 = bb1 & 0xFFFF0000u;
                unsigned int h = (bb0 >> 16) | t1;
                ls += __uint_as_float(h << 16) + __uint_as_float(t1);
                wv[k] = h;
            }
            lsum += ls;
            uint32x4 u0 = { wv[0], wv[1], wv[2], wv[3] };  // regs 0..7  -> j=(e&3)+8*(e>>2)+4hi
            uint32x4 u1 = { wv[4], wv[5], wv[6], wv[7] };  // regs 8..15 -> j=16+...
            bf16x8 pa0 = __builtin_bit_cast(bf16x8, u0);
            bf16x8 pa1 = __builtin_bit_cast(bf16x8, u1);
            // Z += P * V: B slot (hi,e) reads swizzled V^T row d, groups m=0..3
            #pragma unroll
            for (int dt = 0; dt < 2; ++dt) {
                int d = dt * 32 + i5;
                int dh = d >> 3;
                int rowb = d * LDQ + 4 * hi;
                bf16x4 v0a = *(const bf16x4*)&Vc[rowb + (((js * 4 + 0) ^ dh) << 3)];
                bf16x4 v0b = *(const bf16x4*)&Vc[rowb + (((js * 4 + 1) ^ dh) << 3)];
                bf16x4 v1a = *(const bf16x4*)&Vc[rowb + (((js * 4 + 2) ^ dh) << 3)];
                bf16x4 v1b = *(const bf16x4*)&Vc[rowb + (((js * 4 + 3) ^ dh) << 3)];
                bf16x8 vb0 = __builtin_shufflevector(v0a, v0b, 0, 1, 2, 3, 4, 5, 6, 7);
                bf16x8 vb1 = __builtin_shufflevector(v1a, v1b, 0, 1, 2, 3, 4, 5, 6, 7);
                if (dt == 0) {
                    Of0 = __builtin_amdgcn_mfma_f32_32x32x16_bf16(pa0, vb0, Of0, 0, 0, 0);
                    Of0 = __builtin_amdgcn_mfma_f32_32x32x16_bf16(pa1, vb1, Of0, 0, 0, 0);
                } else {
                    Of1 = __builtin_amdgcn_mfma_f32_32x32x16_bf16(pa0, vb0, Of1, 0, 0, 0);
                    Of1 = __builtin_amdgcn_mfma_f32_32x32x16_bf16(pa1, vb1, Of1, 0, 0, 0);
                }
            }
        }
        __syncthreads();
    }

    // l: partner lane (hi^1) holds the complementary j's for the same i=i5
    float l = lsum + __shfl_xor(lsum, 32);
    float linv = 1.f / l;
    // normalize + stage 128x64 output tile into LDS for coalesced writes
    #pragma unroll
    for (int r = 0; r < 16; ++r) {
        int cr = (r & 3) + 8 * (r >> 2);
        float li = __shfl(linv, cr + 4 * hi);
        int row = w * 32 + cr + 4 * hi;
        sh[row * LDQ + i5]      = f2b(Of0[r] * li);
        sh[row * LDQ + 32 + i5] = f2b(Of1[r] * li);
    }
    __syncthreads();
    int zr = t >> 1, zc = (t & 1) * 32;
    size_t zoff = (size_t)(itile * 128 + zr) * DIM + zc;
    #pragma unroll
    for (int c4 = 0; c4 < 4; ++c4)
        *(float4*)&Zp[zoff + c4 * 8] = *(const float4*)&sh[zr * LDQ + zc + c4 * 8];
}

// ---------------- Kernel 3: out = Z @ Wo (MFMA, fp32 out) ------------------
// M=8192, N=64, K=768. 256 one-wave blocks; 2 m-tiles per wave for ILP.
// (round-6 verbatim)
__global__ __launch_bounds__(64) void out_kernel(
    const ushort* __restrict__ Z, const ushort* __restrict__ Wot,
    float* __restrict__ out)
{
    int m0 = blockIdx.x * 32;
    int lane = threadIdx.x;
    int ln = lane & 15, q = lane >> 4;
    f32x4 acc[2][4];
    #pragma unroll
    for (int u = 0; u < 2; ++u)
        #pragma unroll
        for (int nt = 0; nt < 4; ++nt) acc[u][nt] = (f32x4){0.f, 0.f, 0.f, 0.f};
    for (int kc = 0; kc < 24; ++kc) {
        bf16x8 a0 = *(const bf16x8*)&Z[(size_t)(m0 + ln) * HD + kc * 32 + q * 8];
        bf16x8 a1 = *(const bf16x8*)&Z[(size_t)(m0 + 16 + ln) * HD + kc * 32 + q * 8];
        #pragma unroll
        for (int nt = 0; nt < 4; ++nt) {
            bf16x8 bf = *(const bf16x8*)&Wot[(size_t)(nt * 16 + ln) * HD + kc * 32 + q * 8];
            acc[0][nt] = __builtin_amdgcn_mfma_f32_16x16x32_bf16(a0, bf, acc[0][nt], 0, 0, 0);
            acc[1][nt] = __builtin_amdgcn_mfma_f32_16x16x32_bf16(a1, bf, acc[1][nt], 0, 0, 0);
        }
    }
    #pragma unroll
    for (int u = 0; u < 2; ++u)
        #pragma unroll
        for (int nt = 0; nt < 4; ++nt)
            #pragma unroll
            for (int r = 0; r < 4; ++r)
                out[(size_t)(m0 + u * 16 + q * 4 + r) * DIM + nt * 16 + ln] = acc[u][nt][r];
}

extern "C" void kernel_launch(void* const* d_in, const int* in_sizes, int n_in,
                              void* d_out, int out_size, void* d_ws, size_t ws_size,
                              hipStream_t stream)
{
    const float* x  = (const float*)d_in[0];
    const float* Wq = (const float*)d_in[1];
    const float* Wk = (const float*)d_in[2];
    const float* Wv = (const float*)d_in[3];
    const float* Wo = (const float*)d_in[4];
    float* out = (float*)d_out;

    const size_t n = (size_t)BT * HD;            // 6,291,456
    ushort* Q   = (ushort*)d_ws;
    ushort* K   = Q + n;
    ushort* V   = K + n;                         // attn reads V directly now
    ushort* Z   = V + n;                         // own buffer (no V alias!)
    ushort* Wt  = Z + n;                         // 3*768*64 = 147456 ushorts
    ushort* Wot = Wt + 3 * HD * DIM;             // 49152 ushorts

    prep_w<<<48, 256, 0, stream>>>(Wq, Wk, Wv, Wo, Wt, Wot);
    qkv_kernel<<<dim3(128, 2), 256, 0, stream>>>(x, Wt, Q, K, V);
    attn_kernel<<<dim3(16, 48), 256, 0, stream>>>(Q, K, V, Z);
    out_kernel<<<256, 64, 0, stream>>>(Z, Wot, out);
}

// Round 13
// 176.256 us; speedup vs baseline: 1.0407x; 1.0407x over previous
//
#include <hip/hip_runtime.h>
#include <hip/hip_bf16.h>

// MultiHeadAttention: B=4, T=2048, DIM=64, H=12. fp32 I/O.
// Flat-reshape semantics: QKV are (8192,768) row-major; attention slices are
// contiguous 131072-elem chunks. Roles: queries = K rows (i), keys = Q rows
// (j), values = V rows, softmax over j.
// Round 21: timestamp arithmetic across rounds shows qkv ~= 80us (co-dominant
// with attn; never visible in top-5). (a) qkv stores repacked via the
// VERIFIED vtrans pattern: f2b -> scalar ushort writes to wave-private LDS ->
// __syncthreads -> float4 reads -> 2 coalesced b128 global stores per tile
// (was 16 scattered scalar stores). [NOT the banned f32-stage class.]
// (b) attn: XCD-aware bijective block swizzle (same-slice blocks share L2;
// Q/V slices are re-read 16x) + accumulator chain-breaking (QK 2x2, PV 4
// independent chains, epilogue sums — pure fp reassociation).
// Base otherwise = round-6 best (173.5us): qkv y=6, vtrans, out 256x64.

#define DIM 64
#define NH 12
#define HD 768
#define BT 8192
#define TSEQ 2048
#define NSLICE 48
#define SLICE (TSEQ*DIM)

#define LDQ 72   // LDS row strides (ushorts)
#define LDT 72

typedef unsigned short ushort;
typedef __attribute__((ext_vector_type(8))) short bf16x8;
typedef __attribute__((ext_vector_type(4))) short bf16x4;
typedef __attribute__((ext_vector_type(4))) float f32x4;
typedef __attribute__((ext_vector_type(16))) float f32x16;
typedef __attribute__((ext_vector_type(4))) unsigned int uint32x4;

#define SCALE2 0.18033688011112042f   // 0.125 * log2(e)

__device__ __forceinline__ ushort f2b(float f) {
    union { float f; unsigned int i; } v; v.f = f;
    unsigned int x = v.i;
    return (ushort)((x + 0x7fffu + ((x >> 16) & 1u)) >> 16);  // RNE
}

// ---------------- prep: transpose + convert weights ------------------------
// 48 blocks: z = bx/12 (Wq,Wk,Wv,Wo), tile = bx%12.
__global__ __launch_bounds__(256) void prep_w(
    const float* __restrict__ Wq, const float* __restrict__ Wk,
    const float* __restrict__ Wv, const float* __restrict__ Wo,
    ushort* __restrict__ Wt, ushort* __restrict__ Wot)
{
    __shared__ float tile[64][65];
    int bx = blockIdx.x;
    int z = bx / 12, bt = bx % 12;
    const float* __restrict__ IN = (z == 0) ? Wq : (z == 1) ? Wk : (z == 2) ? Wv : Wo;
    int inStride  = (z < 3) ? HD : DIM;
    int outStride = (z < 3) ? DIM : HD;
    int rbase = (z < 3) ? 0 : bt * 64;
    int cbase = (z < 3) ? bt * 64 : 0;
    ushort* __restrict__ OUT = (z < 3) ? (Wt + (size_t)z * HD * DIM) : Wot;
    int t = threadIdx.x;
    int r = t >> 2, c0 = (t & 3) * 16;
    #pragma unroll
    for (int cc = 0; cc < 16; cc += 4) {
        float4 a = *(const float4*)&IN[(size_t)(rbase + r) * inStride + cbase + c0 + cc];
        tile[r][c0 + cc] = a.x; tile[r][c0 + cc + 1] = a.y;
        tile[r][c0 + cc + 2] = a.z; tile[r][c0 + cc + 3] = a.w;
    }
    __syncthreads();
    int cl = t >> 2, r0 = (t & 3) * 16;
    ushort tmp[16] __attribute__((aligned(16)));
    #pragma unroll
    for (int rr = 0; rr < 16; ++rr) tmp[rr] = f2b(tile[r0 + rr][cl]);
    *(float4*)&OUT[(size_t)(cbase + cl) * outStride + rbase + r0] = *(const float4*)tmp;
    *(float4*)&OUT[(size_t)(cbase + cl) * outStride + rbase + r0 + 8] = *(const float4*)&tmp[8];
}

// ---------------- Kernel 1: Q/K/V = x @ W (MFMA; x read as fp32) -----------
// grid (128 row-tiles, 6 col-groups), 256 thr = 4 waves; wave owns 16 rows,
// loops 6 col-tiles. Stores via the VERIFIED vtrans pattern: f2b -> scalar
// ushort writes to wave-private LDS -> barrier -> float4 reads -> 2 coalesced
// b128 global stores (8 rows x 128B each) instead of 16 scattered stores.
__global__ __launch_bounds__(256) void qkv_kernel(
    const float* __restrict__ x, const ushort* __restrict__ Wt,
    ushort* __restrict__ Q, ushort* __restrict__ K, ushort* __restrict__ V)
{
    __shared__ ushort Sst[4][16 * LDT];
    int rt = blockIdx.x, yg = blockIdx.y;
    int t = threadIdx.x, w = t >> 6, lane = t & 63;
    int ln = lane & 15, q = lane >> 4;
    int m0 = rt * 64 + w * 16;
    ushort* Sw = Sst[w];

    // A-frags from fp32 x, converted in-reg (once per wave)
    float4 xa = *(const float4*)&x[(size_t)(m0 + ln) * DIM + q * 8];
    float4 xb_ = *(const float4*)&x[(size_t)(m0 + ln) * DIM + q * 8 + 4];
    float4 xc = *(const float4*)&x[(size_t)(m0 + ln) * DIM + 32 + q * 8];
    float4 xd = *(const float4*)&x[(size_t)(m0 + ln) * DIM + 32 + q * 8 + 4];
    ushort ta[8] __attribute__((aligned(16)));
    ushort tb[8] __attribute__((aligned(16)));
    ta[0]=f2b(xa.x); ta[1]=f2b(xa.y); ta[2]=f2b(xa.z); ta[3]=f2b(xa.w);
    ta[4]=f2b(xb_.x); ta[5]=f2b(xb_.y); ta[6]=f2b(xb_.z); ta[7]=f2b(xb_.w);
    tb[0]=f2b(xc.x); tb[1]=f2b(xc.y); tb[2]=f2b(xc.z); tb[3]=f2b(xc.w);
    tb[4]=f2b(xd.x); tb[5]=f2b(xd.y); tb[6]=f2b(xd.z); tb[7]=f2b(xd.w);
    bf16x8 af0 = *(const bf16x8*)ta;
    bf16x8 af1 = *(const bf16x8*)tb;

    int rr8 = lane >> 3, c8 = (lane & 7) * 8;
    for (int cc = 0; cc < 6; ++cc) {
        int ct = yg * 6 + cc;
        int which = ct / 12;              // block-uniform (yg fixed)
        int col0 = (ct % 12) * 64;
        const ushort* __restrict__ Wz = Wt + (size_t)which * HD * DIM;  // (768x64)
        ushort* __restrict__ Y = (which == 0) ? Q : (which == 1) ? K : V;
        float sc = (which == 0) ? SCALE2 : 1.f;
        f32x4 acc[4];
        #pragma unroll
        for (int nt = 0; nt < 4; ++nt) {
            int n = col0 + nt * 16 + ln;
            bf16x8 bf0 = *(const bf16x8*)&Wz[(size_t)n * DIM + q * 8];
            bf16x8 bf1 = *(const bf16x8*)&Wz[(size_t)n * DIM + 32 + q * 8];
            f32x4 a = (f32x4){0.f, 0.f, 0.f, 0.f};
            a = __builtin_amdgcn_mfma_f32_16x16x32_bf16(af0, bf0, a, 0, 0, 0);
            a = __builtin_amdgcn_mfma_f32_16x16x32_bf16(af1, bf1, a, 0, 0, 0);
            acc[nt] = a;
        }
        // vtrans-writer flavor: f2b then scalar ushort LDS writes
        #pragma unroll
        for (int nt = 0; nt < 4; ++nt)
            #pragma unroll
            for (int r = 0; r < 4; ++r)
                Sw[(q * 4 + r) * LDT + nt * 16 + ln] = f2b(acc[nt][r] * sc);
        __syncthreads();
        // vtrans-reader flavor: float4 reads, coalesced 128B-row stores
        #pragma unroll
        for (int p = 0; p < 2; ++p) {
            int rr = p * 8 + rr8;
            float4 v = *(const float4*)&Sw[rr * LDT + c8];
            *(float4*)&Y[(size_t)(m0 + rr) * HD + col0 + c8] = v;
        }
        __syncthreads();
    }
}

// ---------------- Kernel 1b: Vt[s][d][t] = V[s][t][d] ----------------------
// XOR-swizzled transposed scalar writes (banks spread), vector reads un-swizzle.
__global__ __launch_bounds__(256) void vtrans_kernel(
    const ushort* __restrict__ V, ushort* __restrict__ Vt)
{
    __shared__ ushort tileT[64 * LDT];
    int tt = blockIdx.x, s = blockIdx.y;
    const ushort* __restrict__ Vp = V + (size_t)s * SLICE;
    ushort* __restrict__ Vo = Vt + (size_t)s * SLICE;
    int t = threadIdx.x;
    int r = t >> 3, c = (t & 7) * 8;
    ushort va[8] __attribute__((aligned(16)));
    ushort vb[8] __attribute__((aligned(16)));
    *(float4*)va = *(const float4*)&Vp[(size_t)(tt * 64 + r) * DIM + c];
    *(float4*)vb = *(const float4*)&Vp[(size_t)(tt * 64 + r + 32) * DIM + c];
    int g0 = ((r >> 3) ^ (c >> 3)) * 8 + (r & 7);
    int g1 = (((r + 32) >> 3) ^ (c >> 3)) * 8 + (r & 7);
    #pragma unroll
    for (int k = 0; k < 8; ++k) {
        tileT[(c + k) * LDT + g0] = va[k];
        tileT[(c + k) * LDT + g1] = vb[k];
    }
    __syncthreads();
    #pragma unroll
    for (int j = 0; j < 2; ++j) {
        int flat = t + 256 * j;
        int d = flat >> 3, tg = flat & 7;
        int sg = tg ^ ((d >> 3) & 7);
        float4 vv = *(const float4*)&tileT[d * LDT + sg * 8];
        *(float4*)&Vo[(size_t)d * TSEQ + tt * 64 + tg * 8] = vv;
    }
}

// ---------------- Kernel 2: MFMA flash attention (32x32, reg-P, dbuf) ------
// r13 core + (a) XCD-aware bijective swizzle: bid -> (xcd = bid&7) owns 6
// consecutive slices; same-slice blocks co-locate on one XCD's L2 (Q/V slices
// re-read 16x). (b) chain-break: QK = 2 independent 2-MFMA chains; PV = 4
// independent chains (Of0a/b, Of1a/b), summed in the epilogue.
__global__ __launch_bounds__(256, 3) void attn_kernel(
    const ushort* __restrict__ Qs, const ushort* __restrict__ Ks,
    const ushort* __restrict__ Vts, ushort* __restrict__ Zs)
{
    __shared__ ushort sh[4 * 64 * LDQ];   // [Qt0][Qt1][Vt0][Vt1]; epilogue reuses
    int bid = blockIdx.x + (blockIdx.y << 4);   // gridDim.x = 16
    int xcd = bid & 7, idx = bid >> 3;          // assume XCD = linear%8
    int s = xcd * 6 + idx % 6;                  // bijective over [0,48)
    int itile = idx / 6;                        // [0,16)
    const ushort* __restrict__ Qp = Qs + (size_t)s * SLICE;
    const ushort* __restrict__ Kp = Ks + (size_t)s * SLICE;
    const ushort* __restrict__ Vp = Vts + (size_t)s * SLICE;   // [64][2048]
    ushort* __restrict__ Zp = Zs + (size_t)s * SLICE;
    int t = threadIdx.x, w = t >> 6, lane = t & 63;
    int i5 = lane & 31, hi = lane >> 5;

    // K fragments (B-operand): lane holds K[i0+i5][c*16 + hi*8 + e]
    bf16x8 kf[4];
    {
        size_t krow = (size_t)(itile * 128 + w * 32 + i5) * DIM;
        #pragma unroll
        for (int c = 0; c < 4; ++c)
            kf[c] = *(const bf16x8*)&Kp[krow + c * 16 + hi * 8];
    }

    f32x16 Of0a, Of0b, Of1a, Of1b;
    #pragma unroll
    for (int r = 0; r < 16; ++r) { Of0a[r] = 0.f; Of0b[r] = 0.f; Of1a[r] = 0.f; Of1b[r] = 0.f; }
    float lsum = 0.f;

    int sr = t >> 3, sc = (t & 7) * 8;
    const ushort* qsrc0 = &Qp[(size_t)sr * DIM + sc];
    const ushort* qsrc1 = &Qp[(size_t)(sr + 32) * DIM + sc];
    const ushort* vsrc0 = &Vp[(size_t)sr * TSEQ + sc];
    const ushort* vsrc1 = &Vp[(size_t)(sr + 32) * TSEQ + sc];

    // prologue: tile 0 -> buf 0, prefetch tile 1 into regs
    float4 qa0 = *(const float4*)qsrc0;
    float4 qa1 = *(const float4*)qsrc1;
    float4 va0 = *(const float4*)vsrc0;
    float4 va1 = *(const float4*)vsrc1;
    *(float4*)&sh[sr * LDQ + sc] = qa0;
    *(float4*)&sh[(sr + 32) * LDQ + sc] = qa1;
    *(float4*)&sh[2 * 64 * LDQ + sr * LDQ + sc] = va0;
    *(float4*)&sh[2 * 64 * LDQ + (sr + 32) * LDQ + sc] = va1;
    qa0 = *(const float4*)(qsrc0 + 64 * DIM);
    qa1 = *(const float4*)(qsrc1 + 64 * DIM);
    va0 = *(const float4*)(vsrc0 + 64);
    va1 = *(const float4*)(vsrc1 + 64);
    __syncthreads();

    for (int tt = 0; tt < 32; ++tt) {
        int ib = tt & 1;
        const ushort* Qc = sh + ib * (64 * LDQ);
        const ushort* Vc = sh + (2 + ib) * (64 * LDQ);
        // stage next tile into the other buffer; issue loads for tile tt+2
        if (tt < 31) {
            ushort* Qn = sh + (ib ^ 1) * (64 * LDQ);
            ushort* Vn = sh + (2 + (ib ^ 1)) * (64 * LDQ);
            *(float4*)&Qn[sr * LDQ + sc] = qa0;
            *(float4*)&Qn[(sr + 32) * LDQ + sc] = qa1;
            *(float4*)&Vn[sr * LDQ + sc] = va0;
            *(float4*)&Vn[(sr + 32) * LDQ + sc] = va1;
            if (tt < 30) {
                size_t qo = (size_t)(tt + 2) * 64 * DIM;
                int vo = (tt + 2) * 64;
                qa0 = *(const float4*)(qsrc0 + qo);
                qa1 = *(const float4*)(qsrc1 + qo);
                va0 = *(const float4*)(vsrc0 + vo);
                va1 = *(const float4*)(vsrc1 + vo);
            }
        }
        #pragma unroll
        for (int js = 0; js < 2; ++js) {
            // S^T (32j x 32i), Q pre-scaled: two independent 2-MFMA chains
            f32x16 sa, sb;
            #pragma unroll
            for (int r = 0; r < 16; ++r) { sa[r] = 0.f; sb[r] = 0.f; }
            bf16x8 a0 = *(const bf16x8*)&Qc[(js * 32 + i5) * LDQ + 0 * 16 + hi * 8];
            bf16x8 a1 = *(const bf16x8*)&Qc[(js * 32 + i5) * LDQ + 1 * 16 + hi * 8];
            bf16x8 a2 = *(const bf16x8*)&Qc[(js * 32 + i5) * LDQ + 2 * 16 + hi * 8];
            bf16x8 a3 = *(const bf16x8*)&Qc[(js * 32 + i5) * LDQ + 3 * 16 + hi * 8];
            sa = __builtin_amdgcn_mfma_f32_32x32x16_bf16(a0, kf[0], sa, 0, 0, 0);
            sb = __builtin_amdgcn_mfma_f32_32x32x16_bf16(a2, kf[2], sb, 0, 0, 0);
            sa = __builtin_amdgcn_mfma_f32_32x32x16_bf16(a1, kf[1], sa, 0, 0, 0);
            sb = __builtin_amdgcn_mfma_f32_32x32x16_bf16(a3, kf[3], sb, 0, 0, 0);
            // p = exp2(S); truncation-pack pairs (low short = even reg);
            // l summed from the truncated values (matches P exactly)
            unsigned wv[8];
            float ls = 0.f;
            #pragma unroll
            for (int k = 0; k < 8; ++k) {
                float p0 = __builtin_amdgcn_exp2f(sa[2 * k] + sb[2 * k]);
                float p1 = __builtin_amdgcn_exp2f(sa[2 * k + 1] + sb[2 * k + 1]);
                unsigned int b0 = __float_as_uint(p0), b1 = __float_as_uint(p1);
                unsigned int t1 = b1 & 0xFFFF0000u;
                unsigned int h = (b0 >> 16) | t1;
                ls += __uint_as_float(h << 16) + __uint_as_float(t1);
                wv[k] = h;
            }
            lsum += ls;
            uint32x4 u0 = { wv[0], wv[1], wv[2], wv[3] };  // regs 0..7  -> j=(e&3)+8*(e>>2)+4hi
            uint32x4 u1 = { wv[4], wv[5], wv[6], wv[7] };  // regs 8..15 -> j=16+...
            bf16x8 pa0 = __builtin_bit_cast(bf16x8, u0);
            bf16x8 pa1 = __builtin_bit_cast(bf16x8, u1);
            // Z += P * V: 4 independent accumulator chains (a/b split)
            #pragma unroll
            for (int dt = 0; dt < 2; ++dt) {
                int vbase = (dt * 32 + i5) * LDQ + js * 32 + 4 * hi;
                bf16x4 v0a = *(const bf16x4*)&Vc[vbase];
                bf16x4 v0b = *(const bf16x4*)&Vc[vbase + 8];
                bf16x4 v1a = *(const bf16x4*)&Vc[vbase + 16];
                bf16x4 v1b = *(const bf16x4*)&Vc[vbase + 24];
                bf16x8 vb0 = __builtin_shufflevector(v0a, v0b, 0, 1, 2, 3, 4, 5, 6, 7);
                bf16x8 vb1 = __builtin_shufflevector(v1a, v1b, 0, 1, 2, 3, 4, 5, 6, 7);
                if (dt == 0) {
                    Of0a = __builtin_amdgcn_mfma_f32_32x32x16_bf16(pa0, vb0, Of0a, 0, 0, 0);
                    Of0b = __builtin_amdgcn_mfma_f32_32x32x16_bf16(pa1, vb1, Of0b, 0, 0, 0);
                } else {
                    Of1a = __builtin_amdgcn_mfma_f32_32x32x16_bf16(pa0, vb0, Of1a, 0, 0, 0);
                    Of1b = __builtin_amdgcn_mfma_f32_32x32x16_bf16(pa1, vb1, Of1b, 0, 0, 0);
                }
            }
        }
        __syncthreads();
    }

    // l: partner lane (hi^1) holds the complementary j's for the same i=i5
    float l = lsum + __shfl_xor(lsum, 32);
    float linv = 1.f / l;
    // normalize + stage 128x64 output tile into LDS for coalesced writes
    #pragma unroll
    for (int r = 0; r < 16; ++r) {
        int cr = (r & 3) + 8 * (r >> 2);
        float li = __shfl(linv, cr + 4 * hi);
        int row = w * 32 + cr + 4 * hi;
        sh[row * LDQ + i5]      = f2b((Of0a[r] + Of0b[r]) * li);
        sh[row * LDQ + 32 + i5] = f2b((Of1a[r] + Of1b[r]) * li);
    }
    __syncthreads();
    int zr = t >> 1, zc = (t & 1) * 32;
    size_t zoff = (size_t)(itile * 128 + zr) * DIM + zc;
    #pragma unroll
    for (int c4 = 0; c4 < 4; ++c4)
        *(float4*)&Zp[zoff + c4 * 8] = *(const float4*)&sh[zr * LDQ + zc + c4 * 8];
}

// ---------------- Kernel 3: out = Z @ Wo (MFMA, fp32 out) ------------------
// M=8192, N=64, K=768. 256 one-wave blocks; 2 m-tiles per wave for ILP.
// (round-6 verbatim)
__global__ __launch_bounds__(64) void out_kernel(
    const ushort* __restrict__ Z, const ushort* __restrict__ Wot,
    float* __restrict__ out)
{
    int m0 = blockIdx.x * 32;
    int lane = threadIdx.x;
    int ln = lane & 15, q = lane >> 4;
    f32x4 acc[2][4];
    #pragma unroll
    for (int u = 0; u < 2; ++u)
        #pragma unroll
        for (int nt = 0; nt < 4; ++nt) acc[u][nt] = (f32x4){0.f, 0.f, 0.f, 0.f};
    for (int kc = 0; kc < 24; ++kc) {
        bf16x8 a0 = *(const bf16x8*)&Z[(size_t)(m0 + ln) * HD + kc * 32 + q * 8];
        bf16x8 a1 = *(const bf16x8*)&Z[(size_t)(m0 + 16 + ln) * HD + kc * 32 + q * 8];
        #pragma unroll
        for (int nt = 0; nt < 4; ++nt) {
            bf16x8 bf = *(const bf16x8*)&Wot[(size_t)(nt * 16 + ln) * HD + kc * 32 + q * 8];
            acc[0][nt] = __builtin_amdgcn_mfma_f32_16x16x32_bf16(a0, bf, acc[0][nt], 0, 0, 0);
            acc[1][nt] = __builtin_amdgcn_mfma_f32_16x16x32_bf16(a1, bf, acc[1][nt], 0, 0, 0);
        }
    }
    #pragma unroll
    for (int u = 0; u < 2; ++u)
        #pragma unroll
        for (int nt = 0; nt < 4; ++nt)
            #pragma unroll
            for (int r = 0; r < 4; ++r)
                out[(size_t)(m0 + u * 16 + q * 4 + r) * DIM + nt * 16 + ln] = acc[u][nt][r];
}

extern "C" void kernel_launch(void* const* d_in, const int* in_sizes, int n_in,
                              void* d_out, int out_size, void* d_ws, size_t ws_size,
                              hipStream_t stream)
{
    const float* x  = (const float*)d_in[0];
    const float* Wq = (const float*)d_in[1];
    const float* Wk = (const float*)d_in[2];
    const float* Wv = (const float*)d_in[3];
    const float* Wo = (const float*)d_in[4];
    float* out = (float*)d_out;

    const size_t n = (size_t)BT * HD;            // 6,291,456
    ushort* Q   = (ushort*)d_ws;
    ushort* K   = Q + n;
    ushort* V   = K + n;                         // Z aliases V (V dead after vtrans)
    ushort* Vt  = V + n;
    ushort* Wt  = Vt;                            // Wt lives only until qkv done;
    ushort* Wot = Vt + n;                        //   then vtrans overwrites with Vt
    ushort* Z   = V;

    prep_w<<<48, 256, 0, stream>>>(Wq, Wk, Wv, Wo, Wt, Wot);
    qkv_kernel<<<dim3(128, 6), 256, 0, stream>>>(x, Wt, Q, K, V);
    vtrans_kernel<<<dim3(32, 48), 256, 0, stream>>>(V, Vt);
    attn_kernel<<<dim3(16, 48), 256, 0, stream>>>(Q, K, Vt, Z);
    out_kernel<<<256, 64, 0, stream>>>(Z, Wot, out);
}